// Round 1
// baseline (241.271 us; speedup 1.0000x reference)
//
#include <hip/hip_runtime.h>

// MMSE-PIC detector: B=32768, M=16, S=8, QAM16 Gray, 2 iterations.
// Round 7: register-resident forward elimination. The 16x25 augmented
// elimination now lives entirely in VGPRs: lane = (row, colgroup-of-7),
// pivot via v_readlane, multiplier column via ds_bpermute (precomputed
// index + immediate offset), pivot row via ds_swizzle immediates.
// Removes ~350 strided LDS ops + 15 WSYNCs + their address math per wave.

#define EPS_F 1e-4f
#define INV_SQRT10 0.31622776601683794f
#define WSYNC() __builtin_amdgcn_wave_barrier()

__device__ __forceinline__ float rcpf(float x) { return __builtin_amdgcn_rcpf(x); }
__device__ __forceinline__ float rsqf(float x) { return __builtin_amdgcn_rsqf(x); }
__device__ __forceinline__ float rdlane(float v, int l) {
    return __uint_as_float(__builtin_amdgcn_readlane(__float_as_uint(v), l));
}
template<int OFF>
__device__ __forceinline__ float swzf(float v) {
    return __uint_as_float(__builtin_amdgcn_ds_swizzle(__float_as_uint(v), OFF));
}
__device__ __forceinline__ float bpermf(int byteidx, float v) {
    return __uint_as_float(__builtin_amdgcn_ds_bpermute(byteidx, __float_as_uint(v)));
}
// xor-butterfly swizzle patterns (BitMode: offset = xor<<10 | or<<5 | and)
#define SWX1 0x041F
#define SWX2 0x081F
#define SWX4 0x101F

__device__ __forceinline__ float pt_re(int p) {
    return (1.0f - 2.0f * (float)((p >> 3) & 1)) * (1.0f + 2.0f * (float)((p >> 1) & 1)) * INV_SQRT10;
}
__device__ __forceinline__ float pt_im(int p) {
    return (1.0f - 2.0f * (float)((p >> 2) & 1)) * (1.0f + 2.0f * (float)(p & 1)) * INV_SQRT10;
}

__global__ __launch_bounds__(128, 4)
void mmse_pic_kernel(const float* __restrict__ y_re, const float* __restrict__ y_im,
                     const float* __restrict__ h_re, const float* __restrict__ h_im,
                     const float* __restrict__ prior,
                     const float* __restrict__ s_re, const float* __restrict__ s_im,
                     float* __restrict__ out)
{
    const int lane = threadIdx.x & 63;
    const int w    = threadIdx.x >> 6;            // wave id in block = sub-batch
    const int b    = blockIdx.x * 2 + w;
    const size_t bs = (size_t)b;

    __shared__ float2 Sc[2][16][28];   // load staging: [S(0-15) | h(16-23) | y(24)]; cols 16-24 reused for whitened W
    __shared__ float2 xc_[2][8];
    __shared__ float2 ymc_[2][8];
    __shared__ float  vx_[2][8], ne_[2][8];
    __shared__ float  lsig[2][64];
    __shared__ float  logit_[2][8][20];
    __shared__ float  llrD_[2][8][4];

    // ---- load (vectorized, interleave re/im into float2) ----
    {
        const float4* pr4 = (const float4*)(s_re + bs * 256);
        const float4* pi4 = (const float4*)(s_im + bs * 256);
        float4 vr = pr4[lane], vi = pi4[lane];
        int r = lane >> 2, c0 = (lane & 3) << 2;
        Sc[w][r][c0+0] = make_float2(vr.x, vi.x);
        Sc[w][r][c0+1] = make_float2(vr.y, vi.y);
        Sc[w][r][c0+2] = make_float2(vr.z, vi.z);
        Sc[w][r][c0+3] = make_float2(vr.w, vi.w);
        if (lane < 32) {
            const float4* hr4 = (const float4*)(h_re + bs * 128);
            const float4* hi4 = (const float4*)(h_im + bs * 128);
            float4 hr = hr4[lane], hi = hi4[lane];
            int row = lane >> 1, col = 16 + ((lane & 1) << 2);
            Sc[w][row][col+0] = make_float2(hr.x, hi.x);
            Sc[w][row][col+1] = make_float2(hr.y, hi.y);
            Sc[w][row][col+2] = make_float2(hr.z, hi.z);
            Sc[w][row][col+3] = make_float2(hr.w, hi.w);
        }
        if (lane < 16) Sc[w][lane][24] = make_float2(y_re[bs*16+lane], y_im[bs*16+lane]);
        if (lane < 32) ((float*)llrD_[w])[lane] = prior[bs*32 + lane];
    }
    WSYNC();

    // ---- register-resident forward elimination on [S | h y] ----
    // lane layout: rr = row (0-15), qq = column group; group q owns cols 7q..7q+6
    // (g0: 0-6, g1: 7-13, g2: 14-20, g3: 21-24 + 3 dead slots).
    const int rr = lane & 15, qq = lane >> 4;
    float2 cc[7];
    {
        #pragma unroll
        for (int j = 0; j < 7; ++j) cc[j] = Sc[w][rr][qq * 7 + j];
    }
    float irs = 0.f;                       // rsqrt of this lane's row diagonal
    const int idxr4 = rr << 2;             // bpermute byte index base: 4*row

    // step K: pivot d = A[K][K] (readlane, real), multiplier col A[rr][K]
    // gathered from group GK via bpermute, pivot row via ds_swizzle
    // src = (l&0x10)|K within each 32-half. Rows <= K frozen by m=0.
#define ELIM(K) { \
        constexpr int GK = (K) / 7, SK = (K) % 7; \
        const float dk = rdlane(cc[SK].x, GK * 16 + (K)); \
        const float invd = rcpf(dk); \
        if (rr == (K)) irs = rsqf(dk); \
        const float akr = bpermf(idxr4 + GK * 64, cc[SK].x); \
        const float aki = bpermf(idxr4 + GK * 64, cc[SK].y); \
        float mr = akr * invd, mi = aki * invd; \
        if (rr <= (K)) { mr = 0.f; mi = 0.f; } \
        _Pragma("unroll") \
        for (int j = 0; j < 7; ++j) { \
            float pvr = swzf<(((K) << 5) | 0x10)>(cc[j].x); \
            float pvi = swzf<(((K) << 5) | 0x10)>(cc[j].y); \
            cc[j].x -= mr * pvr - mi * pvi; \
            cc[j].y -= mr * pvi + mi * pvr; \
        } }

    ELIM(0)  ELIM(1)  ELIM(2)  ELIM(3)  ELIM(4)  ELIM(5)  ELIM(6)
    ELIM(7)  ELIM(8)  ELIM(9)  ELIM(10) ELIM(11) ELIM(12) ELIM(13) ELIM(14)
#undef ELIM
    {   // last diagonal (row 15): owner lane = g2*16+15 = 47, slot (15-14)=1
        const float d15 = rdlane(cc[1].x, 47);
        if (rr == 15) irs = rsqf(d15);
    }

    // ---- scale by rsqrt(d_row) and write back whitened [h|y] (cols 16-24) ----
    if (qq == 2) {
        #pragma unroll
        for (int j = 2; j < 7; ++j)          // cols 16..20
            Sc[w][rr][14 + j] = make_float2(cc[j].x * irs, cc[j].y * irs);
    } else if (qq == 3) {
        #pragma unroll
        for (int j = 0; j < 4; ++j)          // cols 21..24
            Sc[w][rr][21 + j] = make_float2(cc[j].x * irs, cc[j].y * irs);
    }
    WSYNC();

    // ---- Gram g[i][j] = (Wh^H Wh)[i][j] (1 entry/lane), y_mf = Wh^H Wy ----
    const int s = lane >> 3, u = lane & 7;
    float g_re = 0.f, g_im = 0.f, ym_r = 0.f, ym_i = 0.f;
    #pragma unroll
    for (int m = 0; m < 16; ++m) {
        float2 a  = Sc[w][m][16 + s];
        float2 x  = Sc[w][m][16 + u];
        float2 xy = Sc[w][m][24];
        g_re += a.x*x.x + a.y*x.y;      // conj(a)*x
        g_im += a.x*x.y - a.y*x.x;
        ym_r += a.x*xy.x + a.y*xy.y;
        ym_i += a.x*xy.y - a.y*xy.x;
    }
    if (u == 0) ymc_[w][s] = make_float2(ym_r, ym_i);
    WSYNC();

    const float pr = pt_re(u), pi2 = pt_im(u), pe = pr*pr + pi2*pi2;  // pt(u+8) = (-pr, pi2)
    float llr_a_reg = 0.f;

    for (int it = 0; it < 2; ++it) {
        // log-sigmoid table: one distinct value per lane
        {
            int ts = lane >> 3, tk = (lane >> 1) & 3, sg = lane & 1;
            float v = llrD_[w][ts][tk];
            float x = sg ? v : -v;
            lsig[w][lane] = fminf(x, 0.f) - __logf(1.0f + __expf(-fabsf(x)));
        }
        if (lane < 32) llr_a_reg = ((float*)llrD_[w])[lane];
        WSYNC();
        // symbol logits for p=u (l0) and p=u+8 (l1), in registers
        int base = s << 3;
        float lc = lsig[w][base | 2 | ((u >> 2) & 1)]
                 + lsig[w][base | 4 | ((u >> 1) & 1)]
                 + lsig[w][base | 6 | (u & 1)];
        float l0 = lc + lsig[w][base];
        float l1 = lc + lsig[w][base | 1];
        // moments: swizzle-butterfly over the 8 lanes of stream s
        {
            float mx = fmaxf(l0, l1);
            mx = fmaxf(mx, swzf<SWX1>(mx));
            mx = fmaxf(mx, swzf<SWX2>(mx));
            mx = fmaxf(mx, swzf<SWX4>(mx));
            float w0 = __expf(l0 - mx), w1 = __expf(l1 - mx);
            float a = w0 + w1, dw = w0 - w1;
            float se = a, mr = dw * pr, mi = a * pi2, e2 = a * pe;
            se += swzf<SWX1>(se); mr += swzf<SWX1>(mr); mi += swzf<SWX1>(mi); e2 += swzf<SWX1>(e2);
            se += swzf<SWX2>(se); mr += swzf<SWX2>(mr); mi += swzf<SWX2>(mi); e2 += swzf<SWX2>(e2);
            se += swzf<SWX4>(se); mr += swzf<SWX4>(mr); mi += swzf<SWX4>(mi); e2 += swzf<SWX4>(e2);
            if (u == 0) {
                float inv = rcpf(se);
                float mxr = mr*inv, mxi = mi*inv;
                xc_[w][s] = make_float2(mxr, mxi);
                vx_[w][s] = e2*inv - (mxr*mxr + mxi*mxi);
            }
        }
        WSYNC();
        // setup: b_i = y_mf[i] - (g x)_i, A = I + g diag(var), C = g
        float2 xj = xc_[w][u];
        float vj = vx_[w][u];
        float tr = g_re*xj.x - g_im*xj.y;
        float ti = g_re*xj.y + g_im*xj.x;
        tr += swzf<SWX1>(tr); ti += swzf<SWX1>(ti);
        tr += swzf<SWX2>(tr); ti += swzf<SWX2>(ti);
        tr += swzf<SWX4>(tr); ti += swzf<SWX4>(ti);
        float2 ym = ymc_[w][s];
        float br_ = ym.x - tr, bi_ = ym.y - ti;
        float Ar = g_re*vj + ((s == u) ? 1.f : 0.f);
        float Ai = g_im*vj;
        float Cr = g_re, Ci = g_im;
        // inner unnormalized GJ on [A | b | C]: registers; pivot via v_readlane
        // (uniform), multiplier bcast via ds_swizzle (src=(L&0x38)|K), row bcast
        // via bpermute.
        #define GJ_STEP(K) { \
            float pvr = rdlane(Ar, (K)*9), pvi = rdlane(Ai, (K)*9); \
            int rowsrc = ((K)<<3)|u; \
            float rAr = __shfl(Ar, rowsrc), rAi = __shfl(Ai, rowsrc); \
            float rCr = __shfl(Cr, rowsrc), rCi = __shfl(Ci, rowsrc); \
            float rbr = __shfl(br_, rowsrc), rbi = __shfl(bi_, rowsrc); \
            float cAr = swzf<(((K)<<5)|0x18)>(Ar), cAi = swzf<(((K)<<5)|0x18)>(Ai); \
            float id2 = rcpf(pvr*pvr + pvi*pvi); \
            float ipr2 = pvr*id2, ipi2 = -pvi*id2; \
            float mr2 = cAr*ipr2 - cAi*ipi2; \
            float mi2 = cAr*ipi2 + cAi*ipr2; \
            if (s == (K)) { mr2 = 0.f; mi2 = 0.f; } \
            Ar  -= mr2*rAr - mi2*rAi;  Ai  -= mr2*rAi + mi2*rAr; \
            Cr  -= mr2*rCr - mi2*rCi;  Ci  -= mr2*rCi + mi2*rCr; \
            br_ -= mr2*rbr - mi2*rbi;  bi_ -= mr2*rbi + mi2*rbr; }
        GJ_STEP(0) GJ_STEP(1) GJ_STEP(2) GJ_STEP(3)
        GJ_STEP(4) GJ_STEP(5) GJ_STEP(6) GJ_STEP(7)
        #undef GJ_STEP
        // extraction on diagonal lanes: z = (w + Cii*x)/mu, no_eff
        if (s == u) {
            float id3 = rcpf(Ar*Ar + Ai*Ai);
            float ipr3 = Ar*id3, ipi3 = -Ai*id3;
            float wr = br_*ipr3 - bi_*ipi3;
            float wi = br_*ipi3 + bi_*ipr3;
            float ccr = Cr*ipr3 - Ci*ipi3;
            float cci = Cr*ipi3 + Ci*ipr3;
            float mu = ccr;
            float im = rcpf(mu);
            float zr = (wr + ccr*xj.x - cci*xj.y) * im;
            float zi = (wi + ccr*xj.y + cci*xj.x) * im;
            xc_[w][s] = make_float2(zr, zi);
            ne_[w][s] = fmaxf(1.f - vx_[w][s]*mu, EPS_F) * im;
        }
        WSYNC();
        // demap: 2 points per lane
        {
            float2 xh = xc_[w][s];
            float idn = rcpf(ne_[w][s]);
            float dr0 = xh.x - pr, dr1 = xh.x + pr, di = xh.y - pi2;
            logit_[w][s][u]     = l0 - (dr0*dr0 + di*di) * idn;
            logit_[w][s][u + 8] = l1 - (dr1*dr1 + di*di) * idn;
        }
        WSYNC();
        // max-log LLR: lane = (s2, bit kb, half); max over 8 matching points
        {
            int s2 = lane >> 3, kb = (lane >> 1) & 3, half = lane & 1;
            int bitpos = 3 - kb;
            float m = -1e30f;
            #pragma unroll
            for (int q = 0; q < 8; ++q) {
                int low  = q & ((1 << bitpos) - 1);
                int high = (q >> bitpos) << (bitpos + 1);
                int p = high | (half << bitpos) | low;
                m = fmaxf(m, logit_[w][s2][p]);
            }
            float other = swzf<SWX1>(m);
            if (half == 1) llrD_[w][s2][kb] = m - other;   // l1 - l0
        }
        WSYNC();
    }

    if (lane < 32) out[bs*32 + lane] = ((float*)llrD_[w])[lane] - llr_a_reg;
}

extern "C" void kernel_launch(void* const* d_in, const int* in_sizes, int n_in,
                              void* d_out, int out_size, void* d_ws, size_t ws_size,
                              hipStream_t stream) {
    const float* y_re  = (const float*)d_in[0];
    const float* y_im  = (const float*)d_in[1];
    const float* h_re  = (const float*)d_in[2];
    const float* h_im  = (const float*)d_in[3];
    const float* prior = (const float*)d_in[4];
    const float* s_re  = (const float*)d_in[5];
    const float* s_im  = (const float*)d_in[6];
    float* out = (float*)d_out;

    const int B = in_sizes[0] / 16;
    mmse_pic_kernel<<<dim3(B / 2), dim3(128), 0, stream>>>(
        y_re, y_im, h_re, h_im, prior, s_re, s_im, out);
}